// Round 5
// baseline (632.448 us; speedup 1.0000x reference)
//
#include <hip/hip_runtime.h>
#include <hip/hip_bf16.h>
#include <stdint.h>

#define E_EDGES 80000
#define N_NODES 10000
#define HD      64
#define DDIST   128
#define DIN     256
#define NCOEF   49
#define W3OUT   224   // M0(7) * C_SPH(32)
#define WROW    2401  // 49*49

// needed wigner columns: l*(l+1) for l=0..6 -> {0,2,6,12,20,30,42}
#define WMASK ((1ull<<0)|(1ull<<2)|(1ull<<6)|(1ull<<12)|(1ull<<20)|(1ull<<30)|(1ull<<42))

// Compile-time destination LUT: rel (0..2400) -> row*8+slot, or -1 if the
// column rel%49 is not one of {0,2,6,12,20,30,42}.
struct Lut { short v[WROW]; };
static constexpr Lut make_lut() {
    Lut L{};
    for (int rel = 0; rel < WROW; ++rel) {
        const int row = rel / 49;
        const int col = rel - row * 49;
        int slot = -1;
        const int cols[7] = {0, 2, 6, 12, 20, 30, 42};
        for (int s = 0; s < 7; ++s) if (cols[s] == col) slot = s;
        L.v[rel] = (slot >= 0) ? (short)(row * 8 + slot) : (short)-1;
    }
    return L;
}
__device__ const Lut d_lut = make_lut();

// ---------------------------------------------------------------------------
// Kernel A: per-edge MLP (frozen since round 3).  Zeroes cnt[] as it goes.
// ---------------------------------------------------------------------------
__global__ __launch_bounds__(256) void k_mlp(
    const int* __restrict__ an, const int* __restrict__ ei,
    const float* __restrict__ ed,
    const float* __restrict__ semb, const float* __restrict__ temb,
    const float* __restrict__ W1, const float* __restrict__ b1,
    const float* __restrict__ g1, const float* __restrict__ be1,
    const float* __restrict__ W2, const float* __restrict__ b2,
    const float* __restrict__ g2, const float* __restrict__ be2,
    const float* __restrict__ W3, const float* __restrict__ b3,
    int* __restrict__ cnt, float* __restrict__ y3)
{
    __shared__ float xT[4][DIN * 8];
    __shared__ float hT[4][HD * 8];
    __shared__ float h2T[4][HD * 8];
    const int tid  = threadIdx.x;

    const int zi = blockIdx.x * 256 + tid;
    if (zi < N_NODES) cnt[zi] = 0;

    const int wave = tid >> 6;
    const int lane = tid & 63;
    const int e0   = blockIdx.x * 32 + wave * 8;
    float* __restrict__ xw  = xT[wave];
    float* __restrict__ hw  = hT[wave];
    float* __restrict__ h2w = h2T[wave];

    #pragma unroll
    for (int ep = 0; ep < 8; ep++) {
        const int e = e0 + ep;
        const float2 edv = *(const float2*)(ed + e * DDIST + lane * 2);
        xw[(2 * lane) * 8 + ep]     = edv.x;
        xw[(2 * lane + 1) * 8 + ep] = edv.y;
        const int sn = ei[e];
        const int tn = ei[E_EDGES + e];
        xw[(128 + lane) * 8 + ep] = semb[an[sn] * HD + lane];
        xw[(192 + lane) * 8 + ep] = temb[an[tn] * HD + lane];
    }
    __syncthreads();

    float acc[8];
    #pragma unroll
    for (int ep = 0; ep < 8; ep++) acc[ep] = 0.f;
    #pragma unroll 4
    for (int k = 0; k < DIN; k++) {
        const float w  = W1[k * HD + lane];
        const float4 xa = *(const float4*)(xw + k * 8);
        const float4 xb = *(const float4*)(xw + k * 8 + 4);
        acc[0] = fmaf(w, xa.x, acc[0]); acc[1] = fmaf(w, xa.y, acc[1]);
        acc[2] = fmaf(w, xa.z, acc[2]); acc[3] = fmaf(w, xa.w, acc[3]);
        acc[4] = fmaf(w, xb.x, acc[4]); acc[5] = fmaf(w, xb.y, acc[5]);
        acc[6] = fmaf(w, xb.z, acc[6]); acc[7] = fmaf(w, xb.w, acc[7]);
    }
    {
        const float bb = b1[lane], gg = g1[lane], be = be1[lane];
        #pragma unroll
        for (int ep = 0; ep < 8; ep++) {
            float h = acc[ep] + bb;
            float s = h, s2 = h * h;
            #pragma unroll
            for (int off = 32; off > 0; off >>= 1) {
                s  += __shfl_xor(s,  off, 64);
                s2 += __shfl_xor(s2, off, 64);
            }
            const float mu  = s * (1.f / 64.f);
            const float var = fmaxf(s2 * (1.f / 64.f) - mu * mu, 0.f);
            const float t   = (h - mu) * rsqrtf(var + 1e-5f) * gg + be;
            hw[lane * 8 + ep] = t / (1.f + expf(-t));
        }
    }
    __syncthreads();

    #pragma unroll
    for (int ep = 0; ep < 8; ep++) acc[ep] = 0.f;
    #pragma unroll 4
    for (int k = 0; k < HD; k++) {
        const float w  = W2[k * HD + lane];
        const float4 xa = *(const float4*)(hw + k * 8);
        const float4 xb = *(const float4*)(hw + k * 8 + 4);
        acc[0] = fmaf(w, xa.x, acc[0]); acc[1] = fmaf(w, xa.y, acc[1]);
        acc[2] = fmaf(w, xa.z, acc[2]); acc[3] = fmaf(w, xa.w, acc[3]);
        acc[4] = fmaf(w, xb.x, acc[4]); acc[5] = fmaf(w, xb.y, acc[5]);
        acc[6] = fmaf(w, xb.z, acc[6]); acc[7] = fmaf(w, xb.w, acc[7]);
    }
    {
        const float bb = b2[lane], gg = g2[lane], be = be2[lane];
        #pragma unroll
        for (int ep = 0; ep < 8; ep++) {
            float h = acc[ep] + bb;
            float s = h, s2 = h * h;
            #pragma unroll
            for (int off = 32; off > 0; off >>= 1) {
                s  += __shfl_xor(s,  off, 64);
                s2 += __shfl_xor(s2, off, 64);
            }
            const float mu  = s * (1.f / 64.f);
            const float var = fmaxf(s2 * (1.f / 64.f) - mu * mu, 0.f);
            const float t   = (h - mu) * rsqrtf(var + 1e-5f) * gg + be;
            h2w[lane * 8 + ep] = t / (1.f + expf(-t));
        }
    }
    __syncthreads();

    #pragma unroll
    for (int chunk = 0; chunk < 4; chunk++) {
        const int ch = chunk * 64 + lane;
        const bool valid = (ch < W3OUT);
        float a2[8];
        #pragma unroll
        for (int ep = 0; ep < 8; ep++) a2[ep] = 0.f;
        #pragma unroll 4
        for (int k = 0; k < HD; k++) {
            const float w  = valid ? W3[k * W3OUT + ch] : 0.f;
            const float4 xa = *(const float4*)(h2w + k * 8);
            const float4 xb = *(const float4*)(h2w + k * 8 + 4);
            a2[0] = fmaf(w, xa.x, a2[0]); a2[1] = fmaf(w, xa.y, a2[1]);
            a2[2] = fmaf(w, xa.z, a2[2]); a2[3] = fmaf(w, xa.w, a2[3]);
            a2[4] = fmaf(w, xb.x, a2[4]); a2[5] = fmaf(w, xb.y, a2[5]);
            a2[6] = fmaf(w, xb.z, a2[6]); a2[7] = fmaf(w, xb.w, a2[7]);
        }
        if (valid) {
            const float bb3 = b3[ch];
            #pragma unroll
            for (int ep = 0; ep < 8; ep++)
                y3[(e0 + ep) * W3OUT + ch] = (a2[ep] + bb3) * (1.0f / 5.862f);
        }
    }
}

// ---------------------------------------------------------------------------
// CSR build (frozen)
// ---------------------------------------------------------------------------
__global__ void k_count(const int* __restrict__ ei, int* __restrict__ cnt) {
    const int e = blockIdx.x * 256 + threadIdx.x;
    if (e < E_EDGES) atomicAdd(&cnt[ei[E_EDGES + e]], 1);
}

__global__ __launch_bounds__(1024) void k_scan(const int* __restrict__ cnt,
                                               int* __restrict__ offs,
                                               int* __restrict__ cursor) {
    __shared__ int wsum[16];
    __shared__ int carry_s;
    const int tid  = threadIdx.x;
    const int lane = tid & 63;
    const int wid  = tid >> 6;
    if (tid == 0) carry_s = 0;
    __syncthreads();
    for (int base = 0; base < N_NODES; base += 1024) {
        const int idx = base + tid;
        const int v = (idx < N_NODES) ? cnt[idx] : 0;
        int s = v;
        #pragma unroll
        for (int off = 1; off < 64; off <<= 1) {
            const int t = __shfl_up(s, off, 64);
            if (lane >= off) s += t;
        }
        if (lane == 63) wsum[wid] = s;
        __syncthreads();
        if (wid == 0) {
            const int t = (lane < 16) ? wsum[lane] : 0;
            int ss = t;
            #pragma unroll
            for (int off = 1; off < 16; off <<= 1) {
                const int u = __shfl_up(ss, off, 64);
                if (lane >= off) ss += u;
            }
            if (lane < 16) wsum[lane] = ss - t;
        }
        __syncthreads();
        const int carry = carry_s;
        const int excl = carry + wsum[wid] + s - v;
        if (idx < N_NODES) { offs[idx] = excl; cursor[idx] = excl; }
        __syncthreads();
        if (tid == 1023) carry_s = carry + wsum[15] + s;
    }
    __syncthreads();
    if (tid == 0) offs[N_NODES] = carry_s;
}

__global__ void k_scatter(const int* __restrict__ ei, int* __restrict__ cursor,
                          int* __restrict__ eids) {
    const int e = blockIdx.x * 256 + threadIdx.x;
    if (e < E_EDGES) {
        const int pos = atomicAdd(&cursor[ei[E_EDGES + e]], 1);
        eids[pos] = e;
    }
}

// ---------------------------------------------------------------------------
// Kernel B: round-3 structure (block per node, coalesced float4 stream,
// depth-1 pipeline) with the div-chain commit replaced by a compile-time
// LUT staged in LDS (ds_read_u16 + predicated ds_write).
// LAUNCHED TWICE this round for time attribution (idempotent).
// ---------------------------------------------------------------------------
__global__ __launch_bounds__(256) void k_out(
    const float* __restrict__ wig, const float* __restrict__ y3,
    const int* __restrict__ offs, const int* __restrict__ eids,
    float* __restrict__ out)
{
    __shared__ __align__(16) float wl[NCOEF * 8];   // [i][slot], padded to 8
    __shared__ __align__(16) float yl[W3OUT];       // [l*32 + c]
    __shared__ short lut_s[WROW + 1];
    const int n   = blockIdx.x;
    const int tid = threadIdx.x;
    const int c   = tid & 31;
    const int rr  = tid >> 5;         // 0..7
    const int beg = offs[n];
    const int end = offs[n + 1];

    // stage the compile-time LUT into LDS (1200 ints + 1 short)
    {
        const int* __restrict__ lsrc = (const int*)d_lut.v;
        int* __restrict__ ldst = (int*)lut_s;
        for (int j = tid; j < 1200; j += 256) ldst[j] = lsrc[j];
        if (tid == 0) lut_s[2400] = d_lut.v[2400];
    }

    float acc[7];
    #pragma unroll
    for (int r = 0; r < 7; r++) acc[r] = 0.f;

    const float4* __restrict__ wig4 = (const float4*)wig;
    const size_t NF4_TOTAL = ((size_t)E_EDGES * WROW) >> 2;

    float4 v0, v1, v2, yv;
    int d = 0;

    #define KOUT_ISSUE(E) do {                                              \
        const size_t rs = (size_t)(E) * WROW;                               \
        const size_t B  = rs >> 2;                                          \
        d = (int)(rs & 3);                                                  \
        v0 = make_float4(0.f,0.f,0.f,0.f); v1 = v0; v2 = v0;                \
        const size_t j0 = B + tid, j1 = j0 + 256, j2 = j0 + 512;            \
        if (j0 < NF4_TOTAL)               v0 = wig4[j0];                    \
        if (j1 < NF4_TOTAL)               v1 = wig4[j1];                    \
        if (tid < 89 && j2 < NF4_TOTAL)   v2 = wig4[j2];                    \
        if (tid < 56) yv = ((const float4*)(y3 + (size_t)(E) * W3OUT))[tid];\
    } while (0)

    #define KOUT_UNPACK(VV, R) do {                                         \
        const float xx[4] = {(VV).x, (VV).y, (VV).z, (VV).w};               \
        _Pragma("unroll")                                                   \
        for (int k = 0; k < 4; k++) {                                       \
            const int rel = 1024 * (R) + 4 * tid + k - d;                   \
            if (rel >= 0 && rel < WROW) {                                   \
                const int idx = lut_s[rel];                                 \
                if (idx >= 0) wl[idx] = xx[k];                              \
            }                                                               \
        }                                                                   \
    } while (0)

    #define KOUT_COMMIT() do {                                              \
        KOUT_UNPACK(v0, 0); KOUT_UNPACK(v1, 1); KOUT_UNPACK(v2, 2);         \
        if (tid < 56) ((float4*)yl)[tid] = yv;                              \
    } while (0)

    if (beg < end) {
        KOUT_ISSUE(eids[beg]);
        __syncthreads();               // LUT staged (first use is in COMMIT)
        KOUT_COMMIT();
    }

    for (int ie = beg; ie < end; ie++) {
        __syncthreads();                       // staged LDS visible
        if (ie + 1 < end) {
            const int e2 = eids[ie + 1];
            KOUT_ISSUE(e2);
        }
        float yr[7];
        #pragma unroll
        for (int l = 0; l < 7; l++) yr[l] = yl[l * 32 + c];
        #pragma unroll
        for (int r = 0; r < 7; r++) {
            const int i = r * 8 + rr;
            if (i < NCOEF) {
                const float4 wa = *(const float4*)(wl + i * 8);
                const float4 wb = *(const float4*)(wl + i * 8 + 4);
                acc[r] += wa.x * yr[0] + wa.y * yr[1] + wa.z * yr[2] + wa.w * yr[3]
                        + wb.x * yr[4] + wb.y * yr[5] + wb.z * yr[6];
            }
        }
        __syncthreads();                       // everyone done reading LDS
        if (ie + 1 < end)
            KOUT_COMMIT();
    }

    #pragma unroll
    for (int r = 0; r < 7; r++) {
        const int i = r * 8 + rr;
        if (i < NCOEF) out[(size_t)n * (NCOEF * 32) + i * 32 + c] = acc[r];
    }
}

// ---------------------------------------------------------------------------
extern "C" void kernel_launch(void* const* d_in, const int* in_sizes, int n_in,
                              void* d_out, int out_size, void* d_ws, size_t ws_size,
                              hipStream_t stream)
{
    const int*   an   = (const int*)  d_in[0];
    const int*   ei   = (const int*)  d_in[1];
    const float* ed   = (const float*)d_in[2];
    const float* wig  = (const float*)d_in[3];
    const float* semb = (const float*)d_in[4];
    const float* temb = (const float*)d_in[5];
    const float* W1   = (const float*)d_in[6];
    const float* b1   = (const float*)d_in[7];
    const float* g1   = (const float*)d_in[8];
    const float* be1  = (const float*)d_in[9];
    const float* W2   = (const float*)d_in[10];
    const float* b2   = (const float*)d_in[11];
    const float* g2   = (const float*)d_in[12];
    const float* be2  = (const float*)d_in[13];
    const float* W3   = (const float*)d_in[14];
    const float* b3   = (const float*)d_in[15];
    float* out = (float*)d_out;

    char* ws = (char*)d_ws;
    const size_t y3_bytes = (size_t)E_EDGES * W3OUT * sizeof(float); // 71.68 MB
    float* y3     = (float*)ws;
    int*   cnt    = (int*)(ws + y3_bytes);
    int*   offs   = cnt + N_NODES;
    int*   cursor = offs + N_NODES + 1;
    int*   eids   = cursor + N_NODES;
    const size_t need = y3_bytes +
        sizeof(int) * ((size_t)N_NODES + (N_NODES + 1) + N_NODES + E_EDGES);
    if (ws_size < need) return;

    k_mlp<<<E_EDGES / 32, 256, 0, stream>>>(an, ei, ed, semb, temb,
                                            W1, b1, g1, be1,
                                            W2, b2, g2, be2, W3, b3, cnt, y3);
    k_count<<<(E_EDGES + 255) / 256, 256, 0, stream>>>(ei, cnt);
    k_scan<<<1, 1024, 0, stream>>>(cnt, offs, cursor);
    k_scatter<<<(E_EDGES + 255) / 256, 256, 0, stream>>>(ei, cursor, eids);
    // Launched twice ON PURPOSE (idempotent): dur_us delta vs round 3
    // attributes k_out's share of total time.
    k_out<<<N_NODES, 256, 0, stream>>>(wig, y3, offs, eids, out);
    k_out<<<N_NODES, 256, 0, stream>>>(wig, y3, offs, eids, out);
}

// Round 6
// 376.967 us; speedup vs baseline: 1.6777x; 1.6777x over previous
//
#include <hip/hip_runtime.h>
#include <hip/hip_bf16.h>
#include <stdint.h>

#define E_EDGES 80000
#define N_NODES 10000
#define HD      64
#define DDIST   128
#define DIN     256
#define NCOEF   49
#define W3OUT   224   // M0(7) * C_SPH(32)
#define WROW    2401  // 49*49

// Compile-time destination LUT: rel (0..2400) -> row*8+slot, or -1 if the
// column rel%49 is not one of {0,2,6,12,20,30,42}.
struct Lut { short v[WROW]; };
static constexpr Lut make_lut() {
    Lut L{};
    for (int rel = 0; rel < WROW; ++rel) {
        const int row = rel / 49;
        const int col = rel - row * 49;
        int slot = -1;
        const int cols[7] = {0, 2, 6, 12, 20, 30, 42};
        for (int s = 0; s < 7; ++s) if (cols[s] == col) slot = s;
        L.v[rel] = (slot >= 0) ? (short)(row * 8 + slot) : (short)-1;
    }
    return L;
}
__device__ const Lut d_lut = make_lut();

struct F8 { float v[8]; };

// ---------------------------------------------------------------------------
// Kernel A (round-6 rewrite): per-edge MLP, 8 edges/wave, 4 waves/block.
//  * Layer 1: x read from GLOBAL at wave-uniform per-edge addresses
//    (readfirstlane'd edge index -> scalar-cache s_load path); zero LDS.
//  * Layer 2: h via LDS broadcast (small).
//  * Layer 3: all 4 N-chunks fused in one k-loop (h2 read once per k).
// ---------------------------------------------------------------------------
__global__ __launch_bounds__(256) void k_mlp(
    const int* __restrict__ an, const int* __restrict__ ei,
    const float* __restrict__ ed,
    const float* __restrict__ semb, const float* __restrict__ temb,
    const float* __restrict__ W1, const float* __restrict__ b1,
    const float* __restrict__ g1, const float* __restrict__ be1,
    const float* __restrict__ W2, const float* __restrict__ b2,
    const float* __restrict__ g2, const float* __restrict__ be2,
    const float* __restrict__ W3, const float* __restrict__ b3,
    int* __restrict__ cnt, float* __restrict__ y3)
{
    __shared__ float hT[4][HD * 8];
    __shared__ float h2T[4][HD * 8];
    const int tid  = threadIdx.x;

    // zero the CSR count array (k_count runs after this kernel)
    const int zi = blockIdx.x * 256 + tid;
    if (zi < N_NODES) cnt[zi] = 0;

    const int wave = tid >> 6;
    const int lane = tid & 63;
    const int e0u  = __builtin_amdgcn_readfirstlane(blockIdx.x * 32 + wave * 8);
    float* __restrict__ hw  = hT[wave];
    float* __restrict__ h2w = h2T[wave];

    float acc[8];
    #pragma unroll
    for (int ep = 0; ep < 8; ep++) acc[ep] = 0.f;

    // ---- layer 1, segment A: edge_distance (k = 0..127) --------------------
    {
        #pragma unroll 2
        for (int kc = 0; kc < 16; kc++) {
            float w[8];
            #pragma unroll
            for (int j = 0; j < 8; j++) w[j] = W1[(kc * 8 + j) * HD + lane];
            #pragma unroll
            for (int ep = 0; ep < 8; ep++) {
                const F8 x = *(const F8*)(ed + (size_t)(e0u + ep) * DDIST + kc * 8);
                acc[ep] = fmaf(w[0], x.v[0], acc[ep]);
                acc[ep] = fmaf(w[1], x.v[1], acc[ep]);
                acc[ep] = fmaf(w[2], x.v[2], acc[ep]);
                acc[ep] = fmaf(w[3], x.v[3], acc[ep]);
                acc[ep] = fmaf(w[4], x.v[4], acc[ep]);
                acc[ep] = fmaf(w[5], x.v[5], acc[ep]);
                acc[ep] = fmaf(w[6], x.v[6], acc[ep]);
                acc[ep] = fmaf(w[7], x.v[7], acc[ep]);
            }
        }
    }
    // ---- layer 1, segment B: src embedding (k = 128..191) ------------------
    {
        const float* xb[8];
        #pragma unroll
        for (int ep = 0; ep < 8; ep++) {
            const int sn = ei[e0u + ep];
            xb[ep] = semb + (size_t)an[sn] * HD;
        }
        #pragma unroll 2
        for (int kc = 0; kc < 8; kc++) {
            float w[8];
            #pragma unroll
            for (int j = 0; j < 8; j++) w[j] = W1[(128 + kc * 8 + j) * HD + lane];
            #pragma unroll
            for (int ep = 0; ep < 8; ep++) {
                const F8 x = *(const F8*)(xb[ep] + kc * 8);
                acc[ep] = fmaf(w[0], x.v[0], acc[ep]);
                acc[ep] = fmaf(w[1], x.v[1], acc[ep]);
                acc[ep] = fmaf(w[2], x.v[2], acc[ep]);
                acc[ep] = fmaf(w[3], x.v[3], acc[ep]);
                acc[ep] = fmaf(w[4], x.v[4], acc[ep]);
                acc[ep] = fmaf(w[5], x.v[5], acc[ep]);
                acc[ep] = fmaf(w[6], x.v[6], acc[ep]);
                acc[ep] = fmaf(w[7], x.v[7], acc[ep]);
            }
        }
    }
    // ---- layer 1, segment C: tgt embedding (k = 192..255) ------------------
    {
        const float* xb[8];
        #pragma unroll
        for (int ep = 0; ep < 8; ep++) {
            const int tn = ei[E_EDGES + e0u + ep];
            xb[ep] = temb + (size_t)an[tn] * HD;
        }
        #pragma unroll 2
        for (int kc = 0; kc < 8; kc++) {
            float w[8];
            #pragma unroll
            for (int j = 0; j < 8; j++) w[j] = W1[(192 + kc * 8 + j) * HD + lane];
            #pragma unroll
            for (int ep = 0; ep < 8; ep++) {
                const F8 x = *(const F8*)(xb[ep] + kc * 8);
                acc[ep] = fmaf(w[0], x.v[0], acc[ep]);
                acc[ep] = fmaf(w[1], x.v[1], acc[ep]);
                acc[ep] = fmaf(w[2], x.v[2], acc[ep]);
                acc[ep] = fmaf(w[3], x.v[3], acc[ep]);
                acc[ep] = fmaf(w[4], x.v[4], acc[ep]);
                acc[ep] = fmaf(w[5], x.v[5], acc[ep]);
                acc[ep] = fmaf(w[6], x.v[6], acc[ep]);
                acc[ep] = fmaf(w[7], x.v[7], acc[ep]);
            }
        }
    }

    // ---- LN + silu (1) ------------------------------------------------------
    {
        const float bb = b1[lane], gg = g1[lane], be = be1[lane];
        #pragma unroll
        for (int ep = 0; ep < 8; ep++) {
            float h = acc[ep] + bb;
            float s = h, s2 = h * h;
            #pragma unroll
            for (int off = 32; off > 0; off >>= 1) {
                s  += __shfl_xor(s,  off, 64);
                s2 += __shfl_xor(s2, off, 64);
            }
            const float mu  = s * (1.f / 64.f);
            const float var = fmaxf(s2 * (1.f / 64.f) - mu * mu, 0.f);
            const float t   = (h - mu) * rsqrtf(var + 1e-5f) * gg + be;
            hw[lane * 8 + ep] = t / (1.f + expf(-t));
        }
    }
    __syncthreads();

    // ---- layer 2 ------------------------------------------------------------
    #pragma unroll
    for (int ep = 0; ep < 8; ep++) acc[ep] = 0.f;
    #pragma unroll 4
    for (int k = 0; k < HD; k++) {
        const float w  = W2[k * HD + lane];
        const float4 xa = *(const float4*)(hw + k * 8);
        const float4 xb = *(const float4*)(hw + k * 8 + 4);
        acc[0] = fmaf(w, xa.x, acc[0]); acc[1] = fmaf(w, xa.y, acc[1]);
        acc[2] = fmaf(w, xa.z, acc[2]); acc[3] = fmaf(w, xa.w, acc[3]);
        acc[4] = fmaf(w, xb.x, acc[4]); acc[5] = fmaf(w, xb.y, acc[5]);
        acc[6] = fmaf(w, xb.z, acc[6]); acc[7] = fmaf(w, xb.w, acc[7]);
    }
    {
        const float bb = b2[lane], gg = g2[lane], be = be2[lane];
        #pragma unroll
        for (int ep = 0; ep < 8; ep++) {
            float h = acc[ep] + bb;
            float s = h, s2 = h * h;
            #pragma unroll
            for (int off = 32; off > 0; off >>= 1) {
                s  += __shfl_xor(s,  off, 64);
                s2 += __shfl_xor(s2, off, 64);
            }
            const float mu  = s * (1.f / 64.f);
            const float var = fmaxf(s2 * (1.f / 64.f) - mu * mu, 0.f);
            const float t   = (h - mu) * rsqrtf(var + 1e-5f) * gg + be;
            h2w[lane * 8 + ep] = t / (1.f + expf(-t));
        }
    }
    __syncthreads();

    // ---- layer 3: all 4 chunks fused (x read once per k) --------------------
    float a2[4][8];
    #pragma unroll
    for (int ch = 0; ch < 4; ch++)
        #pragma unroll
        for (int ep = 0; ep < 8; ep++) a2[ch][ep] = 0.f;

    #pragma unroll 2
    for (int k = 0; k < HD; k++) {
        const float w0 = W3[k * W3OUT + lane];
        const float w1 = W3[k * W3OUT + 64 + lane];
        const float w2 = W3[k * W3OUT + 128 + lane];
        const float w3 = (lane < 32) ? W3[k * W3OUT + 192 + lane] : 0.f;
        const float4 xa = *(const float4*)(h2w + k * 8);
        const float4 xb = *(const float4*)(h2w + k * 8 + 4);
        a2[0][0] = fmaf(w0, xa.x, a2[0][0]); a2[0][1] = fmaf(w0, xa.y, a2[0][1]);
        a2[0][2] = fmaf(w0, xa.z, a2[0][2]); a2[0][3] = fmaf(w0, xa.w, a2[0][3]);
        a2[0][4] = fmaf(w0, xb.x, a2[0][4]); a2[0][5] = fmaf(w0, xb.y, a2[0][5]);
        a2[0][6] = fmaf(w0, xb.z, a2[0][6]); a2[0][7] = fmaf(w0, xb.w, a2[0][7]);
        a2[1][0] = fmaf(w1, xa.x, a2[1][0]); a2[1][1] = fmaf(w1, xa.y, a2[1][1]);
        a2[1][2] = fmaf(w1, xa.z, a2[1][2]); a2[1][3] = fmaf(w1, xa.w, a2[1][3]);
        a2[1][4] = fmaf(w1, xb.x, a2[1][4]); a2[1][5] = fmaf(w1, xb.y, a2[1][5]);
        a2[1][6] = fmaf(w1, xb.z, a2[1][6]); a2[1][7] = fmaf(w1, xb.w, a2[1][7]);
        a2[2][0] = fmaf(w2, xa.x, a2[2][0]); a2[2][1] = fmaf(w2, xa.y, a2[2][1]);
        a2[2][2] = fmaf(w2, xa.z, a2[2][2]); a2[2][3] = fmaf(w2, xa.w, a2[2][3]);
        a2[2][4] = fmaf(w2, xb.x, a2[2][4]); a2[2][5] = fmaf(w2, xb.y, a2[2][5]);
        a2[2][6] = fmaf(w2, xb.z, a2[2][6]); a2[2][7] = fmaf(w2, xb.w, a2[2][7]);
        a2[3][0] = fmaf(w3, xa.x, a2[3][0]); a2[3][1] = fmaf(w3, xa.y, a2[3][1]);
        a2[3][2] = fmaf(w3, xa.z, a2[3][2]); a2[3][3] = fmaf(w3, xa.w, a2[3][3]);
        a2[3][4] = fmaf(w3, xb.x, a2[3][4]); a2[3][5] = fmaf(w3, xb.y, a2[3][5]);
        a2[3][6] = fmaf(w3, xb.z, a2[3][6]); a2[3][7] = fmaf(w3, xb.w, a2[3][7]);
    }

    #pragma unroll
    for (int ch = 0; ch < 4; ch++) {
        const int chn = ch * 64 + lane;
        if (ch < 3 || lane < 32) {
            const float bb3 = b3[chn];
            #pragma unroll
            for (int ep = 0; ep < 8; ep++)
                y3[(size_t)(e0u + ep) * W3OUT + chn] =
                    (a2[ch][ep] + bb3) * (1.0f / 5.862f);
        }
    }
}

// ---------------------------------------------------------------------------
// CSR build (frozen)
// ---------------------------------------------------------------------------
__global__ void k_count(const int* __restrict__ ei, int* __restrict__ cnt) {
    const int e = blockIdx.x * 256 + threadIdx.x;
    if (e < E_EDGES) atomicAdd(&cnt[ei[E_EDGES + e]], 1);
}

__global__ __launch_bounds__(1024) void k_scan(const int* __restrict__ cnt,
                                               int* __restrict__ offs,
                                               int* __restrict__ cursor) {
    __shared__ int wsum[16];
    __shared__ int carry_s;
    const int tid  = threadIdx.x;
    const int lane = tid & 63;
    const int wid  = tid >> 6;
    if (tid == 0) carry_s = 0;
    __syncthreads();
    for (int base = 0; base < N_NODES; base += 1024) {
        const int idx = base + tid;
        const int v = (idx < N_NODES) ? cnt[idx] : 0;
        int s = v;
        #pragma unroll
        for (int off = 1; off < 64; off <<= 1) {
            const int t = __shfl_up(s, off, 64);
            if (lane >= off) s += t;
        }
        if (lane == 63) wsum[wid] = s;
        __syncthreads();
        if (wid == 0) {
            const int t = (lane < 16) ? wsum[lane] : 0;
            int ss = t;
            #pragma unroll
            for (int off = 1; off < 16; off <<= 1) {
                const int u = __shfl_up(ss, off, 64);
                if (lane >= off) ss += u;
            }
            if (lane < 16) wsum[lane] = ss - t;
        }
        __syncthreads();
        const int carry = carry_s;
        const int excl = carry + wsum[wid] + s - v;
        if (idx < N_NODES) { offs[idx] = excl; cursor[idx] = excl; }
        __syncthreads();
        if (tid == 1023) carry_s = carry + wsum[15] + s;
    }
    __syncthreads();
    if (tid == 0) offs[N_NODES] = carry_s;
}

__global__ void k_scatter(const int* __restrict__ ei, int* __restrict__ cursor,
                          int* __restrict__ eids) {
    const int e = blockIdx.x * 256 + threadIdx.x;
    if (e < E_EDGES) {
        const int pos = atomicAdd(&cursor[ei[E_EDGES + e]], 1);
        eids[pos] = e;
    }
}

// ---------------------------------------------------------------------------
// Kernel B (round-5 LUT version, single launch): block per node, coalesced
// float4 wigner stream, LDS LUT commit, depth-1 software pipeline.
// ---------------------------------------------------------------------------
__global__ __launch_bounds__(256) void k_out(
    const float* __restrict__ wig, const float* __restrict__ y3,
    const int* __restrict__ offs, const int* __restrict__ eids,
    float* __restrict__ out)
{
    __shared__ __align__(16) float wl[NCOEF * 8];
    __shared__ __align__(16) float yl[W3OUT];
    __shared__ short lut_s[WROW + 1];
    const int n   = blockIdx.x;
    const int tid = threadIdx.x;
    const int c   = tid & 31;
    const int rr  = tid >> 5;
    const int beg = offs[n];
    const int end = offs[n + 1];

    {
        const int* __restrict__ lsrc = (const int*)d_lut.v;
        int* __restrict__ ldst = (int*)lut_s;
        for (int j = tid; j < 1200; j += 256) ldst[j] = lsrc[j];
        if (tid == 0) lut_s[2400] = d_lut.v[2400];
    }

    float acc[7];
    #pragma unroll
    for (int r = 0; r < 7; r++) acc[r] = 0.f;

    const float4* __restrict__ wig4 = (const float4*)wig;
    const size_t NF4_TOTAL = ((size_t)E_EDGES * WROW) >> 2;

    float4 v0, v1, v2, yv;
    int d = 0;

    #define KOUT_ISSUE(E) do {                                              \
        const size_t rs = (size_t)(E) * WROW;                               \
        const size_t B  = rs >> 2;                                          \
        d = (int)(rs & 3);                                                  \
        v0 = make_float4(0.f,0.f,0.f,0.f); v1 = v0; v2 = v0;                \
        const size_t j0 = B + tid, j1 = j0 + 256, j2 = j0 + 512;            \
        if (j0 < NF4_TOTAL)               v0 = wig4[j0];                    \
        if (j1 < NF4_TOTAL)               v1 = wig4[j1];                    \
        if (tid < 89 && j2 < NF4_TOTAL)   v2 = wig4[j2];                    \
        if (tid < 56) yv = ((const float4*)(y3 + (size_t)(E) * W3OUT))[tid];\
    } while (0)

    #define KOUT_UNPACK(VV, R) do {                                         \
        const float xx[4] = {(VV).x, (VV).y, (VV).z, (VV).w};               \
        _Pragma("unroll")                                                   \
        for (int k = 0; k < 4; k++) {                                       \
            const int rel = 1024 * (R) + 4 * tid + k - d;                   \
            if (rel >= 0 && rel < WROW) {                                   \
                const int idx = lut_s[rel];                                 \
                if (idx >= 0) wl[idx] = xx[k];                              \
            }                                                               \
        }                                                                   \
    } while (0)

    #define KOUT_COMMIT() do {                                              \
        KOUT_UNPACK(v0, 0); KOUT_UNPACK(v1, 1); KOUT_UNPACK(v2, 2);         \
        if (tid < 56) ((float4*)yl)[tid] = yv;                              \
    } while (0)

    if (beg < end) {
        KOUT_ISSUE(eids[beg]);
        __syncthreads();               // LUT staged
        KOUT_COMMIT();
    }

    for (int ie = beg; ie < end; ie++) {
        __syncthreads();
        if (ie + 1 < end) {
            const int e2 = eids[ie + 1];
            KOUT_ISSUE(e2);
        }
        float yr[7];
        #pragma unroll
        for (int l = 0; l < 7; l++) yr[l] = yl[l * 32 + c];
        #pragma unroll
        for (int r = 0; r < 7; r++) {
            const int i = r * 8 + rr;
            if (i < NCOEF) {
                const float4 wa = *(const float4*)(wl + i * 8);
                const float4 wb = *(const float4*)(wl + i * 8 + 4);
                acc[r] += wa.x * yr[0] + wa.y * yr[1] + wa.z * yr[2] + wa.w * yr[3]
                        + wb.x * yr[4] + wb.y * yr[5] + wb.z * yr[6];
            }
        }
        __syncthreads();
        if (ie + 1 < end)
            KOUT_COMMIT();
    }

    #pragma unroll
    for (int r = 0; r < 7; r++) {
        const int i = r * 8 + rr;
        if (i < NCOEF) out[(size_t)n * (NCOEF * 32) + i * 32 + c] = acc[r];
    }
}

// ---------------------------------------------------------------------------
extern "C" void kernel_launch(void* const* d_in, const int* in_sizes, int n_in,
                              void* d_out, int out_size, void* d_ws, size_t ws_size,
                              hipStream_t stream)
{
    const int*   an   = (const int*)  d_in[0];
    const int*   ei   = (const int*)  d_in[1];
    const float* ed   = (const float*)d_in[2];
    const float* wig  = (const float*)d_in[3];
    const float* semb = (const float*)d_in[4];
    const float* temb = (const float*)d_in[5];
    const float* W1   = (const float*)d_in[6];
    const float* b1   = (const float*)d_in[7];
    const float* g1   = (const float*)d_in[8];
    const float* be1  = (const float*)d_in[9];
    const float* W2   = (const float*)d_in[10];
    const float* b2   = (const float*)d_in[11];
    const float* g2   = (const float*)d_in[12];
    const float* be2  = (const float*)d_in[13];
    const float* W3   = (const float*)d_in[14];
    const float* b3   = (const float*)d_in[15];
    float* out = (float*)d_out;

    char* ws = (char*)d_ws;
    const size_t y3_bytes = (size_t)E_EDGES * W3OUT * sizeof(float); // 71.68 MB
    float* y3     = (float*)ws;
    int*   cnt    = (int*)(ws + y3_bytes);
    int*   offs   = cnt + N_NODES;
    int*   cursor = offs + N_NODES + 1;
    int*   eids   = cursor + N_NODES;
    const size_t need = y3_bytes +
        sizeof(int) * ((size_t)N_NODES + (N_NODES + 1) + N_NODES + E_EDGES);
    if (ws_size < need) return;

    k_mlp<<<E_EDGES / 32, 256, 0, stream>>>(an, ei, ed, semb, temb,
                                            W1, b1, g1, be1,
                                            W2, b2, g2, be2, W3, b3, cnt, y3);
    k_count<<<(E_EDGES + 255) / 256, 256, 0, stream>>>(ei, cnt);
    k_scan<<<1, 1024, 0, stream>>>(cnt, offs, cursor);
    k_scatter<<<(E_EDGES + 255) / 256, 256, 0, stream>>>(ei, cursor, eids);
    k_out<<<N_NODES, 256, 0, stream>>>(wig, y3, offs, eids, out);
}

// Round 7
// 358.535 us; speedup vs baseline: 1.7640x; 1.0514x over previous
//
#include <hip/hip_runtime.h>
#include <hip/hip_bf16.h>
#include <stdint.h>

#define E_EDGES 80000
#define N_NODES 10000
#define HD      64
#define DDIST   128
#define DIN     256
#define NCOEF   49
#define W3OUT   224   // M0(7) * C_SPH(32)
#define WROW    2401  // 49*49
#define NELEM   90

// Compile-time destination LUT: rel (0..2400) -> row*8+slot, or -1 if the
// column rel%49 is not one of {0,2,6,12,20,30,42}.
struct Lut { short v[WROW]; };
static constexpr Lut make_lut() {
    Lut L{};
    for (int rel = 0; rel < WROW; ++rel) {
        const int row = rel / 49;
        const int col = rel - row * 49;
        int slot = -1;
        const int cols[7] = {0, 2, 6, 12, 20, 30, 42};
        for (int s = 0; s < 7; ++s) if (cols[s] == col) slot = s;
        L.v[rel] = (slot >= 0) ? (short)(row * 8 + slot) : (short)-1;
    }
    return L;
}
__device__ const Lut d_lut = make_lut();

struct F8 { float v[8]; };

// ---------------------------------------------------------------------------
// k_pre: fold the two embedding tables through their W1 slices once.
//   sW1[z][n] = sum_k semb[z][k] * W1[128+k][n]
//   tW1[z][n] = sum_k temb[z][k] * W1[192+k][n]
// 90 blocks x 64 threads; ~1.5 MFLOP total.
// ---------------------------------------------------------------------------
__global__ __launch_bounds__(64) void k_pre(
    const float* __restrict__ semb, const float* __restrict__ temb,
    const float* __restrict__ W1,
    float* __restrict__ sW1, float* __restrict__ tW1)
{
    const int z    = blockIdx.x;
    const int lane = threadIdx.x;
    float sa = 0.f, ta = 0.f;
    #pragma unroll 4
    for (int k = 0; k < HD; k++) {
        const float wk_s = W1[(128 + k) * HD + lane];
        const float wk_t = W1[(192 + k) * HD + lane];
        sa = fmaf(semb[z * HD + k], wk_s, sa);
        ta = fmaf(temb[z * HD + k], wk_t, ta);
    }
    sW1[z * HD + lane] = sa;
    tW1[z * HD + lane] = ta;
}

// ---------------------------------------------------------------------------
// Kernel A (round-7): per-edge MLP, 4 edges/wave, 4 waves/block (16/block).
//  * layer-1 K reduced to 128 (ed part); embedding part comes from sW1/tW1
//    table rows (coalesced, 2 loads/edge).
//  * __launch_bounds__(256,4): target <=128 VGPR -> 16 waves/CU.
// ---------------------------------------------------------------------------
__global__ __launch_bounds__(256, 4) void k_mlp(
    const int* __restrict__ an, const int* __restrict__ ei,
    const float* __restrict__ ed,
    const float* __restrict__ sW1, const float* __restrict__ tW1,
    const float* __restrict__ W1, const float* __restrict__ b1,
    const float* __restrict__ g1, const float* __restrict__ be1,
    const float* __restrict__ W2, const float* __restrict__ b2,
    const float* __restrict__ g2, const float* __restrict__ be2,
    const float* __restrict__ W3, const float* __restrict__ b3,
    int* __restrict__ cnt, float* __restrict__ y3)
{
    __shared__ float hT[4][HD * 4];
    __shared__ float h2T[4][HD * 4];
    const int tid  = threadIdx.x;

    // zero the CSR count array (k_count runs after this kernel)
    const int zi = blockIdx.x * 256 + tid;
    if (zi < N_NODES) cnt[zi] = 0;

    const int wave = tid >> 6;
    const int lane = tid & 63;
    const int e0u  = __builtin_amdgcn_readfirstlane(blockIdx.x * 16 + wave * 4);
    float* __restrict__ hw  = hT[wave];
    float* __restrict__ h2w = h2T[wave];

    // ---- layer 1 init: precomputed embedding contributions ------------------
    float acc[4];
    #pragma unroll
    for (int ep = 0; ep < 4; ep++) {
        const int sn = ei[e0u + ep];
        const int tn = ei[E_EDGES + e0u + ep];
        acc[ep] = sW1[an[sn] * HD + lane] + tW1[an[tn] * HD + lane];
    }

    // ---- layer 1: ed part (k = 0..127) --------------------------------------
    #pragma unroll 2
    for (int kc = 0; kc < 16; kc++) {
        float w[8];
        #pragma unroll
        for (int j = 0; j < 8; j++) w[j] = W1[(kc * 8 + j) * HD + lane];
        #pragma unroll
        for (int ep = 0; ep < 4; ep++) {
            const F8 x = *(const F8*)(ed + (size_t)(e0u + ep) * DDIST + kc * 8);
            acc[ep] = fmaf(w[0], x.v[0], acc[ep]);
            acc[ep] = fmaf(w[1], x.v[1], acc[ep]);
            acc[ep] = fmaf(w[2], x.v[2], acc[ep]);
            acc[ep] = fmaf(w[3], x.v[3], acc[ep]);
            acc[ep] = fmaf(w[4], x.v[4], acc[ep]);
            acc[ep] = fmaf(w[5], x.v[5], acc[ep]);
            acc[ep] = fmaf(w[6], x.v[6], acc[ep]);
            acc[ep] = fmaf(w[7], x.v[7], acc[ep]);
        }
    }

    // ---- LN + silu (1) ------------------------------------------------------
    {
        const float bb = b1[lane], gg = g1[lane], be = be1[lane];
        #pragma unroll
        for (int ep = 0; ep < 4; ep++) {
            float h = acc[ep] + bb;
            float s = h, s2 = h * h;
            #pragma unroll
            for (int off = 32; off > 0; off >>= 1) {
                s  += __shfl_xor(s,  off, 64);
                s2 += __shfl_xor(s2, off, 64);
            }
            const float mu  = s * (1.f / 64.f);
            const float var = fmaxf(s2 * (1.f / 64.f) - mu * mu, 0.f);
            const float t   = (h - mu) * rsqrtf(var + 1e-5f) * gg + be;
            hw[lane * 4 + ep] = t / (1.f + expf(-t));
        }
    }
    __syncthreads();

    // ---- layer 2 ------------------------------------------------------------
    #pragma unroll
    for (int ep = 0; ep < 4; ep++) acc[ep] = 0.f;
    #pragma unroll 4
    for (int k = 0; k < HD; k++) {
        const float w  = W2[k * HD + lane];
        const float4 xa = *(const float4*)(hw + k * 4);
        acc[0] = fmaf(w, xa.x, acc[0]); acc[1] = fmaf(w, xa.y, acc[1]);
        acc[2] = fmaf(w, xa.z, acc[2]); acc[3] = fmaf(w, xa.w, acc[3]);
    }
    {
        const float bb = b2[lane], gg = g2[lane], be = be2[lane];
        #pragma unroll
        for (int ep = 0; ep < 4; ep++) {
            float h = acc[ep] + bb;
            float s = h, s2 = h * h;
            #pragma unroll
            for (int off = 32; off > 0; off >>= 1) {
                s  += __shfl_xor(s,  off, 64);
                s2 += __shfl_xor(s2, off, 64);
            }
            const float mu  = s * (1.f / 64.f);
            const float var = fmaxf(s2 * (1.f / 64.f) - mu * mu, 0.f);
            const float t   = (h - mu) * rsqrtf(var + 1e-5f) * gg + be;
            h2w[lane * 4 + ep] = t / (1.f + expf(-t));
        }
    }
    __syncthreads();

    // ---- layer 3: all 4 chunks fused (h2 read once per k) -------------------
    float a2[4][4];
    #pragma unroll
    for (int ch = 0; ch < 4; ch++)
        #pragma unroll
        for (int ep = 0; ep < 4; ep++) a2[ch][ep] = 0.f;

    #pragma unroll 2
    for (int k = 0; k < HD; k++) {
        const float w0 = W3[k * W3OUT + lane];
        const float w1 = W3[k * W3OUT + 64 + lane];
        const float w2 = W3[k * W3OUT + 128 + lane];
        const float w3 = (lane < 32) ? W3[k * W3OUT + 192 + lane] : 0.f;
        const float4 xa = *(const float4*)(h2w + k * 4);
        a2[0][0] = fmaf(w0, xa.x, a2[0][0]); a2[0][1] = fmaf(w0, xa.y, a2[0][1]);
        a2[0][2] = fmaf(w0, xa.z, a2[0][2]); a2[0][3] = fmaf(w0, xa.w, a2[0][3]);
        a2[1][0] = fmaf(w1, xa.x, a2[1][0]); a2[1][1] = fmaf(w1, xa.y, a2[1][1]);
        a2[1][2] = fmaf(w1, xa.z, a2[1][2]); a2[1][3] = fmaf(w1, xa.w, a2[1][3]);
        a2[2][0] = fmaf(w2, xa.x, a2[2][0]); a2[2][1] = fmaf(w2, xa.y, a2[2][1]);
        a2[2][2] = fmaf(w2, xa.z, a2[2][2]); a2[2][3] = fmaf(w2, xa.w, a2[2][3]);
        a2[3][0] = fmaf(w3, xa.x, a2[3][0]); a2[3][1] = fmaf(w3, xa.y, a2[3][1]);
        a2[3][2] = fmaf(w3, xa.z, a2[3][2]); a2[3][3] = fmaf(w3, xa.w, a2[3][3]);
    }

    #pragma unroll
    for (int ch = 0; ch < 4; ch++) {
        const int chn = ch * 64 + lane;
        if (ch < 3 || lane < 32) {
            const float bb3 = b3[chn];
            #pragma unroll
            for (int ep = 0; ep < 4; ep++)
                y3[(size_t)(e0u + ep) * W3OUT + chn] =
                    (a2[ch][ep] + bb3) * (1.0f / 5.862f);
        }
    }
}

// ---------------------------------------------------------------------------
// CSR build (frozen)
// ---------------------------------------------------------------------------
__global__ void k_count(const int* __restrict__ ei, int* __restrict__ cnt) {
    const int e = blockIdx.x * 256 + threadIdx.x;
    if (e < E_EDGES) atomicAdd(&cnt[ei[E_EDGES + e]], 1);
}

__global__ __launch_bounds__(1024) void k_scan(const int* __restrict__ cnt,
                                               int* __restrict__ offs,
                                               int* __restrict__ cursor) {
    __shared__ int wsum[16];
    __shared__ int carry_s;
    const int tid  = threadIdx.x;
    const int lane = tid & 63;
    const int wid  = tid >> 6;
    if (tid == 0) carry_s = 0;
    __syncthreads();
    for (int base = 0; base < N_NODES; base += 1024) {
        const int idx = base + tid;
        const int v = (idx < N_NODES) ? cnt[idx] : 0;
        int s = v;
        #pragma unroll
        for (int off = 1; off < 64; off <<= 1) {
            const int t = __shfl_up(s, off, 64);
            if (lane >= off) s += t;
        }
        if (lane == 63) wsum[wid] = s;
        __syncthreads();
        if (wid == 0) {
            const int t = (lane < 16) ? wsum[lane] : 0;
            int ss = t;
            #pragma unroll
            for (int off = 1; off < 16; off <<= 1) {
                const int u = __shfl_up(ss, off, 64);
                if (lane >= off) ss += u;
            }
            if (lane < 16) wsum[lane] = ss - t;
        }
        __syncthreads();
        const int carry = carry_s;
        const int excl = carry + wsum[wid] + s - v;
        if (idx < N_NODES) { offs[idx] = excl; cursor[idx] = excl; }
        __syncthreads();
        if (tid == 1023) carry_s = carry + wsum[15] + s;
    }
    __syncthreads();
    if (tid == 0) offs[N_NODES] = carry_s;
}

__global__ void k_scatter(const int* __restrict__ ei, int* __restrict__ cursor,
                          int* __restrict__ eids) {
    const int e = blockIdx.x * 256 + threadIdx.x;
    if (e < E_EDGES) {
        const int pos = atomicAdd(&cursor[ei[E_EDGES + e]], 1);
        eids[pos] = e;
    }
}

// ---------------------------------------------------------------------------
// Kernel B (FROZEN from round 6): block per node, coalesced float4 wigner
// stream, LDS LUT commit, depth-1 software pipeline.
// ---------------------------------------------------------------------------
__global__ __launch_bounds__(256) void k_out(
    const float* __restrict__ wig, const float* __restrict__ y3,
    const int* __restrict__ offs, const int* __restrict__ eids,
    float* __restrict__ out)
{
    __shared__ __align__(16) float wl[NCOEF * 8];
    __shared__ __align__(16) float yl[W3OUT];
    __shared__ short lut_s[WROW + 1];
    const int n   = blockIdx.x;
    const int tid = threadIdx.x;
    const int c   = tid & 31;
    const int rr  = tid >> 5;
    const int beg = offs[n];
    const int end = offs[n + 1];

    {
        const int* __restrict__ lsrc = (const int*)d_lut.v;
        int* __restrict__ ldst = (int*)lut_s;
        for (int j = tid; j < 1200; j += 256) ldst[j] = lsrc[j];
        if (tid == 0) lut_s[2400] = d_lut.v[2400];
    }

    float acc[7];
    #pragma unroll
    for (int r = 0; r < 7; r++) acc[r] = 0.f;

    const float4* __restrict__ wig4 = (const float4*)wig;
    const size_t NF4_TOTAL = ((size_t)E_EDGES * WROW) >> 2;

    float4 v0, v1, v2, yv;
    int d = 0;

    #define KOUT_ISSUE(E) do {                                              \
        const size_t rs = (size_t)(E) * WROW;                               \
        const size_t B  = rs >> 2;                                          \
        d = (int)(rs & 3);                                                  \
        v0 = make_float4(0.f,0.f,0.f,0.f); v1 = v0; v2 = v0;                \
        const size_t j0 = B + tid, j1 = j0 + 256, j2 = j0 + 512;            \
        if (j0 < NF4_TOTAL)               v0 = wig4[j0];                    \
        if (j1 < NF4_TOTAL)               v1 = wig4[j1];                    \
        if (tid < 89 && j2 < NF4_TOTAL)   v2 = wig4[j2];                    \
        if (tid < 56) yv = ((const float4*)(y3 + (size_t)(E) * W3OUT))[tid];\
    } while (0)

    #define KOUT_UNPACK(VV, R) do {                                         \
        const float xx[4] = {(VV).x, (VV).y, (VV).z, (VV).w};               \
        _Pragma("unroll")                                                   \
        for (int k = 0; k < 4; k++) {                                       \
            const int rel = 1024 * (R) + 4 * tid + k - d;                   \
            if (rel >= 0 && rel < WROW) {                                   \
                const int idx = lut_s[rel];                                 \
                if (idx >= 0) wl[idx] = xx[k];                              \
            }                                                               \
        }                                                                   \
    } while (0)

    #define KOUT_COMMIT() do {                                              \
        KOUT_UNPACK(v0, 0); KOUT_UNPACK(v1, 1); KOUT_UNPACK(v2, 2);         \
        if (tid < 56) ((float4*)yl)[tid] = yv;                              \
    } while (0)

    if (beg < end) {
        KOUT_ISSUE(eids[beg]);
        __syncthreads();               // LUT staged
        KOUT_COMMIT();
    }

    for (int ie = beg; ie < end; ie++) {
        __syncthreads();
        if (ie + 1 < end) {
            const int e2 = eids[ie + 1];
            KOUT_ISSUE(e2);
        }
        float yr[7];
        #pragma unroll
        for (int l = 0; l < 7; l++) yr[l] = yl[l * 32 + c];
        #pragma unroll
        for (int r = 0; r < 7; r++) {
            const int i = r * 8 + rr;
            if (i < NCOEF) {
                const float4 wa = *(const float4*)(wl + i * 8);
                const float4 wb = *(const float4*)(wl + i * 8 + 4);
                acc[r] += wa.x * yr[0] + wa.y * yr[1] + wa.z * yr[2] + wa.w * yr[3]
                        + wb.x * yr[4] + wb.y * yr[5] + wb.z * yr[6];
            }
        }
        __syncthreads();
        if (ie + 1 < end)
            KOUT_COMMIT();
    }

    #pragma unroll
    for (int r = 0; r < 7; r++) {
        const int i = r * 8 + rr;
        if (i < NCOEF) out[(size_t)n * (NCOEF * 32) + i * 32 + c] = acc[r];
    }
}

// ---------------------------------------------------------------------------
extern "C" void kernel_launch(void* const* d_in, const int* in_sizes, int n_in,
                              void* d_out, int out_size, void* d_ws, size_t ws_size,
                              hipStream_t stream)
{
    const int*   an   = (const int*)  d_in[0];
    const int*   ei   = (const int*)  d_in[1];
    const float* ed   = (const float*)d_in[2];
    const float* wig  = (const float*)d_in[3];
    const float* semb = (const float*)d_in[4];
    const float* temb = (const float*)d_in[5];
    const float* W1   = (const float*)d_in[6];
    const float* b1   = (const float*)d_in[7];
    const float* g1   = (const float*)d_in[8];
    const float* be1  = (const float*)d_in[9];
    const float* W2   = (const float*)d_in[10];
    const float* b2   = (const float*)d_in[11];
    const float* g2   = (const float*)d_in[12];
    const float* be2  = (const float*)d_in[13];
    const float* W3   = (const float*)d_in[14];
    const float* b3   = (const float*)d_in[15];
    float* out = (float*)d_out;

    char* ws = (char*)d_ws;
    const size_t y3_bytes = (size_t)E_EDGES * W3OUT * sizeof(float); // 71.68 MB
    float* y3     = (float*)ws;
    int*   cnt    = (int*)(ws + y3_bytes);
    int*   offs   = cnt + N_NODES;
    int*   cursor = offs + N_NODES + 1;
    int*   eids   = cursor + N_NODES;
    float* sW1    = (float*)(eids + E_EDGES);
    float* tW1    = sW1 + NELEM * HD;
    const size_t need = y3_bytes +
        sizeof(int) * ((size_t)N_NODES + (N_NODES + 1) + N_NODES + E_EDGES) +
        sizeof(float) * (2 * NELEM * HD);
    if (ws_size < need) return;

    k_pre<<<NELEM, 64, 0, stream>>>(semb, temb, W1, sW1, tW1);
    k_mlp<<<E_EDGES / 16, 256, 0, stream>>>(an, ei, ed, sW1, tW1,
                                            W1, b1, g1, be1,
                                            W2, b2, g2, be2, W3, b3, cnt, y3);
    k_count<<<(E_EDGES + 255) / 256, 256, 0, stream>>>(ei, cnt);
    k_scan<<<1, 1024, 0, stream>>>(cnt, offs, cursor);
    k_scatter<<<(E_EDGES + 255) / 256, 256, 0, stream>>>(ei, cursor, eids);
    k_out<<<N_NODES, 256, 0, stream>>>(wig, y3, offs, eids, out);
}